// Round 4
// baseline (76.355 us; speedup 1.0000x reference)
//
#include <hip/hip_runtime.h>
#include <hip/hip_bf16.h>

// N=8192, D=128. loss = mean(-log(exp(sims_ii)) + 0.5*(log(den_i)+log(den_j)))
// sims = (A @ T^T) * exp(temp); den = row/col sums of exp(sims), diag zeroed.
//
// ws layout (bytes):
//   [0,      2 MiB)  A bf16, FRAGMENT-MAJOR: [r16 0..511][kk 0..3][lane 0..63][8]
//   [2 MiB,  4 MiB)  T bf16, row-major XOR-swizzled chunks (ushort[8192][128])
//   [4 MiB,  8 MiB)  den_i partials float[8192][128]  (slot = bj*2+wc)
//   [8 MiB, 12 MiB)  den_j partials float[8192][128]  (slot = bi*2+wr)
//   [12 MiB,+32 KiB) per-row loss float[8192]

typedef __attribute__((ext_vector_type(8))) __bf16 bf16x8;
typedef __attribute__((ext_vector_type(4))) float  f32x4;

#define GLD16(g, l) __builtin_amdgcn_global_load_lds(                         \
    (const __attribute__((address_space(1))) unsigned int*)(const void*)(g),  \
    (__attribute__((address_space(3))) unsigned int*)(void*)(l), 16, 0, 0)

__device__ __forceinline__ ushort f2bf(float f) {
    union { float f; unsigned u; } v; v.f = f;
    unsigned r = v.u + 0x7fffu + ((v.u >> 16) & 1u);   // RNE (finite inputs)
    return (ushort)(r >> 16);
}

__device__ __forceinline__ float fast_exp2(float x) {
#if __has_builtin(__builtin_amdgcn_exp2f)
    return __builtin_amdgcn_exp2f(x);      // bare v_exp_f32
#else
    return __expf(x * 0.69314718056f);
#endif
}

// VALU-pipe partial-sum step: v += lane(l-n) within each 16-lane DPP row,
// 0-filled at the edge. After n=1,2,4,8 lane 15 holds the 16-lane sum.
template <int CTRL>
__device__ __forceinline__ float dpp_sr_add(float v) {
    int s = __builtin_amdgcn_update_dpp(0, __float_as_int(v), CTRL, 0xf, 0xf, true);
    return v + __int_as_float(s);
}
__device__ __forceinline__ float row16_sum(float v) {
    v = dpp_sr_add<0x111>(v);   // row_shr:1
    v = dpp_sr_add<0x112>(v);   // row_shr:2
    v = dpp_sr_add<0x114>(v);   // row_shr:4
    v = dpp_sr_add<0x118>(v);   // row_shr:8
    return v;                   // valid in lane 15 of each 16-lane row
}

// ---------------------------------------------------------------- kernel 1
// idx < 131072: pack A fragment-major. Frag semantics (R0-verified):
//   lane l of tile (r16,kk) holds A[r16*16 + (l&15)][kk*32 + (l>>4)*8 .. +8]
// else: convert T row-major with chunk XOR swizzle c^(r&7) (byte ^ (r&7)<<4).
__global__ void convert_pack(const float* __restrict__ a,
                             const float* __restrict__ t,
                             ushort* __restrict__ oa,
                             ushort* __restrict__ ot) {
    int idx = blockIdx.x * 256 + threadIdx.x;          // 0 .. 262143
    if (idx < 131072) {
        int l = idx & 63, tile = idx >> 6;
        int kk = tile & 3, r16 = tile >> 2;
        int row = r16 * 16 + (l & 15);
        int k0  = kk * 32 + (l >> 4) * 8;
        const float4* s4 = reinterpret_cast<const float4*>(a + row * 128 + k0);
        float4 f0 = s4[0], f1 = s4[1];
        uint4 o;
        o.x = f2bf(f0.x) | ((unsigned)f2bf(f0.y) << 16);
        o.y = f2bf(f0.z) | ((unsigned)f2bf(f0.w) << 16);
        o.z = f2bf(f1.x) | ((unsigned)f2bf(f1.y) << 16);
        o.w = f2bf(f1.z) | ((unsigned)f2bf(f1.w) << 16);
        *reinterpret_cast<uint4*>(oa + idx * 8) = o;
    } else {
        int loc = idx - 131072;
        int r = loc >> 4, c = loc & 15;
        const float4* s4 = reinterpret_cast<const float4*>(t + r * 128 + c * 8);
        float4 f0 = s4[0], f1 = s4[1];
        uint4 o;
        o.x = f2bf(f0.x) | ((unsigned)f2bf(f0.y) << 16);
        o.y = f2bf(f0.z) | ((unsigned)f2bf(f0.w) << 16);
        o.z = f2bf(f1.x) | ((unsigned)f2bf(f1.y) << 16);
        o.w = f2bf(f1.z) | ((unsigned)f2bf(f1.w) << 16);
        *reinterpret_cast<uint4*>(ot + r * 128 + ((c ^ (r & 7)) << 3)) = o;
    }
}

// ---------------------------------------------------------------- kernel 2
// 128x128 output tile, 4 waves (2x2), K=128 one shot. B via global_load_lds
// (32 KiB); A-frags global->reg before the barrier. Two n-phases reuse a
// 32-AGPR accumulator so total regs fit 4 waves/SIMD; epilogue reductions
// on the VALU pipe (DPP), not DS.
__global__ void __launch_bounds__(256, 4)
gemm_exp(const ushort* __restrict__ Ap, const ushort* __restrict__ Tb,
         const float* __restrict__ temps,
         float* __restrict__ Pi, float* __restrict__ Pj) {
    __shared__ ushort ldsB[128 * 128];                 // 32 KiB
    const int bi = blockIdx.x, bj = blockIdx.y;
    const int tid = threadIdx.x;
    const int wave = tid >> 6, lane = tid & 63;
    const int wr = wave >> 1, wc = wave & 1;
    const int krow = lane >> 4, lcol = lane & 15;

    // stage B tile (contiguous 32 KiB, pre-swizzled)
    const ushort* gB = Tb + bj * 16384;
#pragma unroll
    for (int i = 0; i < 8; ++i) {
        int c = wave * 512 + i * 64;                   // wave-uniform chunk base
        GLD16(gB + (c + lane) * 8, &ldsB[c * 8]);
    }

    // A fragments: coalesced 1 KiB wave-loads, frag-major layout
    bf16x8 af[4][4];
    const ushort* gA = Ap + ((bi * 8 + wr * 4) * 4 * 64 + lane) * 8;
#pragma unroll
    for (int m = 0; m < 4; ++m)
#pragma unroll
        for (int kk = 0; kk < 4; ++kk)
            af[m][kk] = *reinterpret_cast<const bf16x8*>(gA + (m * 4 + kk) * 512);

    const float sc2 = __expf(temps[0]) * 1.44269504f;  // exp(temp)*log2(e)
    __builtin_amdgcn_sched_barrier(0);                 // keep loads above barrier
    __syncthreads();

    float rsum[4][4];
#pragma unroll
    for (int m = 0; m < 4; ++m)
#pragma unroll
        for (int j = 0; j < 4; ++j) rsum[m][j] = 0.f;

#pragma unroll
    for (int half = 0; half < 2; ++half) {
        f32x4 acc[4][2];
#pragma unroll
        for (int m = 0; m < 4; ++m)
#pragma unroll
            for (int n = 0; n < 2; ++n)
                acc[m][n] = (f32x4){0.f, 0.f, 0.f, 0.f};

#pragma unroll
        for (int kk = 0; kk < 4; ++kk) {
            const int k0 = kk * 32 + krow * 8;
            bf16x8 bf[2];
#pragma unroll
            for (int n = 0; n < 2; ++n) {
                int rb = wc * 64 + (half * 2 + n) * 16 + lcol;
                bf[n] = *reinterpret_cast<const bf16x8*>(
                    &ldsB[rb * 128 + (k0 ^ ((rb & 7) << 3))]);
            }
#pragma unroll
            for (int m = 0; m < 4; ++m)
#pragma unroll
                for (int n = 0; n < 2; ++n)
                    acc[m][n] = __builtin_amdgcn_mfma_f32_16x16x32_bf16(af[m][kk], bf[n], acc[m][n], 0, 0, 0);
        }

        // epilogue for these 2 n-fragments
        float csum[2] = {0.f, 0.f};
#pragma unroll
        for (int m = 0; m < 4; ++m)
#pragma unroll
            for (int n = 0; n < 2; ++n)
#pragma unroll
                for (int j = 0; j < 4; ++j) {
                    float v = fast_exp2(acc[m][n][j] * sc2);
                    rsum[m][j] += v;
                    csum[n] += v;
                }
#pragma unroll
        for (int n = 0; n < 2; ++n) {
            float v = csum[n];
            v += __shfl_xor(v, 16); v += __shfl_xor(v, 32);
            if (lane < 16) {
                int col = bj * 128 + wc * 64 + (half * 2 + n) * 16 + lane;
                Pj[col * 128 + bi * 2 + wr] = v;
            }
        }
    }

    // row sums: 16-lane DPP reduce (VALU pipe), writer lane 15 of each row
#pragma unroll
    for (int m = 0; m < 4; ++m)
#pragma unroll
        for (int j = 0; j < 4; ++j) {
            float v = row16_sum(rsum[m][j]);
            if (lcol == 15) {
                int row = bi * 128 + wr * 64 + m * 16 + krow * 4 + j;
                Pi[row * 128 + bj * 2 + wc] = v;
            }
        }
}

// ---------------------------------------------------------------- kernel 3
// One wave per row, 4 rows/block; partials transposed so reads coalesce.
__global__ void finalize_rows(const float* __restrict__ a, const float* __restrict__ t,
                              const float* __restrict__ temps,
                              const float* __restrict__ Pi, const float* __restrict__ Pj,
                              float* __restrict__ loss) {
    const int r = blockIdx.x * 4 + (threadIdx.x >> 6);
    const int l = threadIdx.x & 63;
    const float sc = __expf(temps[0]);
    float deni = Pi[r * 128 + l] + Pi[r * 128 + 64 + l];
    float denj = Pj[r * 128 + l] + Pj[r * 128 + 64 + l];
    float dotp = a[r * 128 + l] * t[r * 128 + l]
               + a[r * 128 + 64 + l] * t[r * 128 + 64 + l];
#pragma unroll
    for (int m = 1; m < 64; m <<= 1) {
        deni += __shfl_xor(deni, m);
        denj += __shfl_xor(denj, m);
        dotp += __shfl_xor(dotp, m);
    }
    if (l == 0) {
        float diag = __expf(sc * dotp);
        float di = fmaxf(deni - diag, 1e-20f);
        float dj = fmaxf(denj - diag, 1e-20f);
        loss[r] = -sc * dotp + 0.5f * (__logf(di) + __logf(dj));
    }
}

// ---------------------------------------------------------------- kernel 4
__global__ void reduce_loss(const float* __restrict__ loss, float* __restrict__ out) {
    __shared__ float wsum[16];
    const int tid = threadIdx.x;   // 1024
    float s = 0.f;
#pragma unroll
    for (int i = 0; i < 8; ++i) s += loss[tid + i * 1024];
#pragma unroll
    for (int m = 1; m < 64; m <<= 1) s += __shfl_xor(s, m);
    if ((tid & 63) == 0) wsum[tid >> 6] = s;
    __syncthreads();
    if (tid == 0) {
        float acc = 0.f;
#pragma unroll
        for (int w = 0; w < 16; ++w) acc += wsum[w];
        out[0] = acc * (1.0f / 8192.0f);
    }
}

extern "C" void kernel_launch(void* const* d_in, const int* in_sizes, int n_in,
                              void* d_out, int out_size, void* d_ws, size_t ws_size,
                              hipStream_t stream) {
    const float* a     = (const float*)d_in[0];
    const float* t     = (const float*)d_in[1];
    const float* temps = (const float*)d_in[2];
    float* out = (float*)d_out;

    char* ws = (char*)d_ws;
    ushort* Ap  = (ushort*)(ws);
    ushort* Tb  = (ushort*)(ws + (2u << 20));
    float*  Pi  = (float*)(ws + (4u << 20));
    float*  Pj  = (float*)(ws + (8u << 20));
    float*  los = (float*)(ws + (12u << 20));

    convert_pack<<<1024, 256, 0, stream>>>(a, t, Ap, Tb);
    gemm_exp<<<dim3(64, 64), 256, 0, stream>>>(Ap, Tb, temps, Pi, Pj);
    finalize_rows<<<2048, 256, 0, stream>>>(a, t, temps, Pi, Pj, los);
    reduce_loss<<<1, 1024, 0, stream>>>(los, out);
}

// Round 5
// 49.080 us; speedup vs baseline: 1.5557x; 1.5557x over previous
//
#include <hip/hip_runtime.h>
#include <hip/hip_bf16.h>

// N=8192, D=128. loss = mean(-log(exp(sims_ii)) + 0.5*(log(den_i)+log(den_j)))
// sims = (A @ T^T) * exp(temp); den = row/col sums of exp(sims), diag zeroed.
//
// ws layout (bytes):
//   [0,      2 MiB)  A bf16, FRAGMENT-MAJOR: [r16 0..511][kk 0..3][lane 0..63][8]
//   [2 MiB,  4 MiB)  T bf16, FRAGMENT-MAJOR (same transform)
//   [4 MiB,  8 MiB)  den_i partials float[8192][128]  (slot = col-strip j)
//   [8 MiB, 10 MiB)  den_j partials float[8192][64]   (slot = row-group rg)
//   [10 MiB,+32 KiB) per-row loss float[8192]

typedef __attribute__((ext_vector_type(8))) __bf16 bf16x8;
typedef __attribute__((ext_vector_type(4))) float  f32x4;

__device__ __forceinline__ ushort f2bf(float f) {
    union { float f; unsigned u; } v; v.f = f;
    unsigned r = v.u + 0x7fffu + ((v.u >> 16) & 1u);   // RNE (finite inputs)
    return (ushort)(r >> 16);
}

__device__ __forceinline__ float fast_exp2(float x) {
#if __has_builtin(__builtin_amdgcn_exp2f)
    return __builtin_amdgcn_exp2f(x);      // bare v_exp_f32
#else
    return __expf(x * 0.69314718056f);
#endif
}

// VALU-pipe partial-sum step: v += lane(l-n) within each 16-lane DPP row,
// 0-filled at the edge. After 1,2,4,8 lane 15 holds the 16-lane sum.
// (HW-verified correct in R3/R4 runs.)
template <int CTRL>
__device__ __forceinline__ float dpp_sr_add(float v) {
    int s = __builtin_amdgcn_update_dpp(0, __float_as_int(v), CTRL, 0xf, 0xf, true);
    return v + __int_as_float(s);
}
__device__ __forceinline__ float row16_sum(float v) {
    v = dpp_sr_add<0x111>(v);   // row_shr:1
    v = dpp_sr_add<0x112>(v);   // row_shr:2
    v = dpp_sr_add<0x114>(v);   // row_shr:4
    v = dpp_sr_add<0x118>(v);   // row_shr:8
    return v;                   // valid in lane 15 of each 16-lane row
}

// ---------------------------------------------------------------- kernel 1
// Both inputs -> fragment-major bf16. Frag semantics (R0-verified):
//   lane l of tile (r16,kk) holds M[r16*16 + (l&15)][kk*32 + (l>>4)*8 .. +8]
__global__ void convert_pack(const float* __restrict__ a,
                             const float* __restrict__ t,
                             ushort* __restrict__ oa,
                             ushort* __restrict__ ot) {
    int idx = blockIdx.x * 256 + threadIdx.x;          // 0 .. 262143
    const float* src = (idx >> 17) ? t : a;
    ushort*      dst = (idx >> 17) ? ot : oa;
    int loc = idx & 131071;
    int l = loc & 63, tile = loc >> 6;
    int kk = tile & 3, r16 = tile >> 2;
    int row = r16 * 16 + (l & 15);
    int k0  = kk * 32 + (l >> 4) * 8;
    const float4* s4 = reinterpret_cast<const float4*>(src + row * 128 + k0);
    float4 f0 = s4[0], f1 = s4[1];
    uint4 o;
    o.x = f2bf(f0.x) | ((unsigned)f2bf(f0.y) << 16);
    o.y = f2bf(f0.z) | ((unsigned)f2bf(f0.w) << 16);
    o.z = f2bf(f1.x) | ((unsigned)f2bf(f1.y) << 16);
    o.w = f2bf(f1.z) | ((unsigned)f2bf(f1.w) << 16);
    *reinterpret_cast<uint4*>(dst + loc * 8) = o;
}

// ---------------------------------------------------------------- kernel 2
// Independent 32x64 wave-tiles, no LDS staging, no main-loop barriers.
// Block = 4 waves sharing one 64-col T-strip (L1 reuse); wave w covers rows
// r=rg*4+w. B streamed in 2 n-phases to keep regs ~105 -> 4 waves/SIMD.
// XCD-bijective swizzle: 16 consecutive col-strips per XCD (L2 locality).
__global__ void __launch_bounds__(256, 4)
gemm_exp(const ushort* __restrict__ Ap, const ushort* __restrict__ Tp,
         const float* __restrict__ temps,
         float* __restrict__ Pi, float* __restrict__ Pj) {
    __shared__ float cs[4][64];
    const int tid = threadIdx.x;
    const int wave = tid >> 6, lane = tid & 63;
    const int krow = lane >> 4, lcol = lane & 15;
    const int fid = blockIdx.y * 128 + blockIdx.x;     // 0..8191
    const int vid = (fid & 7) * 1024 + (fid >> 3);     // bijective (8192%8==0)
    const int j  = vid >> 6;                           // col-strip 0..127
    const int rg = vid & 63;                           // row-group 0..63
    const int r  = rg * 4 + wave;                      // row-strip 0..255

    const float sc2 = __expf(temps[0]) * 1.44269504f;  // exp(temp)*log2(e)

    // A fragments: 8 coalesced 1 KiB wave-loads (frag-major), held in regs
    bf16x8 af[2][4];
#pragma unroll
    for (int m = 0; m < 2; ++m)
#pragma unroll
        for (int kk = 0; kk < 4; ++kk)
            af[m][kk] = *reinterpret_cast<const bf16x8*>(
                Ap + ((r * 8 + m * 4 + kk) * 64 + lane) * 8);

    float rsum[2][4] = {};

#pragma unroll
    for (int ph = 0; ph < 2; ++ph) {
        bf16x8 bf[2][4];
#pragma unroll
        for (int n = 0; n < 2; ++n)
#pragma unroll
            for (int kk = 0; kk < 4; ++kk)
                bf[n][kk] = *reinterpret_cast<const bf16x8*>(
                    Tp + (((j * 4 + ph * 2 + n) * 4 + kk) * 64 + lane) * 8);

        f32x4 acc[2][2];
#pragma unroll
        for (int m = 0; m < 2; ++m)
#pragma unroll
            for (int n = 0; n < 2; ++n)
                acc[m][n] = (f32x4){0.f, 0.f, 0.f, 0.f};

#pragma unroll
        for (int kk = 0; kk < 4; ++kk)
#pragma unroll
            for (int m = 0; m < 2; ++m)
#pragma unroll
                for (int n = 0; n < 2; ++n)
                    acc[m][n] = __builtin_amdgcn_mfma_f32_16x16x32_bf16(
                        af[m][kk], bf[n][kk], acc[m][n], 0, 0, 0);

        float csum[2] = {0.f, 0.f};
#pragma unroll
        for (int m = 0; m < 2; ++m)
#pragma unroll
            for (int n = 0; n < 2; ++n)
#pragma unroll
                for (int jj = 0; jj < 4; ++jj) {
                    float v = fast_exp2(acc[m][n][jj] * sc2);
                    rsum[m][jj] += v;
                    csum[n] += v;
                }
#pragma unroll
        for (int n = 0; n < 2; ++n) {
            float v = csum[n];
            v += __shfl_xor(v, 16); v += __shfl_xor(v, 32);
            if (lane < 16) cs[wave][(ph * 2 + n) * 16 + lcol] = v;
        }
    }

    // row sums over this wave's 64 cols: DPP reduce, lane 15 of each krow row
#pragma unroll
    for (int m = 0; m < 2; ++m)
#pragma unroll
        for (int jj = 0; jj < 4; ++jj) {
            float v = row16_sum(rsum[m][jj]);
            if (lcol == 15) {
                int row = r * 32 + m * 16 + krow * 4 + jj;
                Pi[row * 128 + j] = v;
            }
        }

    // combine 4 waves' col partials (single end-of-kernel barrier)
    __syncthreads();
    if (tid < 64) {
        float v = cs[0][tid] + cs[1][tid] + cs[2][tid] + cs[3][tid];
        Pj[(j * 64 + tid) * 64 + rg] = v;
    }
}

// ---------------------------------------------------------------- kernel 3
// One wave per row, 4 rows/block; partials transposed so reads coalesce.
__global__ void finalize_rows(const float* __restrict__ a, const float* __restrict__ t,
                              const float* __restrict__ temps,
                              const float* __restrict__ Pi, const float* __restrict__ Pj,
                              float* __restrict__ loss) {
    const int r = blockIdx.x * 4 + (threadIdx.x >> 6);
    const int l = threadIdx.x & 63;
    const float sc = __expf(temps[0]);
    float deni = Pi[r * 128 + l] + Pi[r * 128 + 64 + l];
    float denj = Pj[r * 64 + l];
    float dotp = a[r * 128 + l] * t[r * 128 + l]
               + a[r * 128 + 64 + l] * t[r * 128 + 64 + l];
#pragma unroll
    for (int m = 1; m < 64; m <<= 1) {
        deni += __shfl_xor(deni, m);
        denj += __shfl_xor(denj, m);
        dotp += __shfl_xor(dotp, m);
    }
    if (l == 0) {
        float diag = __expf(sc * dotp);
        float di = fmaxf(deni - diag, 1e-20f);
        float dj = fmaxf(denj - diag, 1e-20f);
        loss[r] = -sc * dotp + 0.5f * (__logf(di) + __logf(dj));
    }
}

// ---------------------------------------------------------------- kernel 4
__global__ void reduce_loss(const float* __restrict__ loss, float* __restrict__ out) {
    __shared__ float wsum[16];
    const int tid = threadIdx.x;   // 1024
    float s = 0.f;
#pragma unroll
    for (int i = 0; i < 8; ++i) s += loss[tid + i * 1024];
#pragma unroll
    for (int m = 1; m < 64; m <<= 1) s += __shfl_xor(s, m);
    if ((tid & 63) == 0) wsum[tid >> 6] = s;
    __syncthreads();
    if (tid == 0) {
        float acc = 0.f;
#pragma unroll
        for (int w = 0; w < 16; ++w) acc += wsum[w];
        out[0] = acc * (1.0f / 8192.0f);
    }
}

extern "C" void kernel_launch(void* const* d_in, const int* in_sizes, int n_in,
                              void* d_out, int out_size, void* d_ws, size_t ws_size,
                              hipStream_t stream) {
    const float* a     = (const float*)d_in[0];
    const float* t     = (const float*)d_in[1];
    const float* temps = (const float*)d_in[2];
    float* out = (float*)d_out;

    char* ws = (char*)d_ws;
    ushort* Ap  = (ushort*)(ws);
    ushort* Tp  = (ushort*)(ws + (2u << 20));
    float*  Pi  = (float*)(ws + (4u << 20));
    float*  Pj  = (float*)(ws + (8u << 20));
    float*  los = (float*)(ws + (10u << 20));

    convert_pack<<<1024, 256, 0, stream>>>(a, t, Ap, Tp);
    gemm_exp<<<dim3(128, 64), 256, 0, stream>>>(Ap, Tp, temps, Pi, Pj);
    finalize_rows<<<2048, 256, 0, stream>>>(a, t, temps, Pi, Pj, los);
    reduce_loss<<<1, 1024, 0, stream>>>(los, out);
}

// Round 6
// 47.071 us; speedup vs baseline: 1.6221x; 1.0427x over previous
//
#include <hip/hip_runtime.h>
#include <hip/hip_bf16.h>

// N=8192, D=128. loss = mean(-log(exp(sims_ii)) + 0.5*(log(den_i)+log(den_j)))
// sims = (A @ T^T) * exp(temp); den = row/col sums of exp(sims), diag zeroed.
//
// Structure (R4 lesson: independent register-resident wave-tiles win):
//   gemm_exp = 2048 blocks x 4 fully independent waves. Wave tile 64x128,
//   A-frags held in regs (64 VGPR), B streamed in 4 phases (32 VGPR reused),
//   zero LDS, zero barriers. 6 B of L1 traffic per output element.
//
// ws layout (bytes):
//   [0,      2 MiB)  A bf16, FRAGMENT-MAJOR: [r16 0..511][kk 0..3][lane 0..63][8]
//   [2 MiB,  4 MiB)  T bf16, FRAGMENT-MAJOR (same transform)
//   [4 MiB,  6 MiB)  den_i partials float[8192][64]   (slot = col-strip j, 128 cols)
//   [6 MiB, 10 MiB)  den_j partials float[8192][128]  (slot = row-strip rs, 64 rows)
//   [10 MiB,+32 KiB) per-row loss float[8192]

typedef __attribute__((ext_vector_type(8))) __bf16 bf16x8;
typedef __attribute__((ext_vector_type(4))) float  f32x4;

__device__ __forceinline__ ushort f2bf(float f) {
    union { float f; unsigned u; } v; v.f = f;
    unsigned r = v.u + 0x7fffu + ((v.u >> 16) & 1u);   // RNE (finite inputs)
    return (ushort)(r >> 16);
}

__device__ __forceinline__ float fast_exp2(float x) {
#if __has_builtin(__builtin_amdgcn_exp2f)
    return __builtin_amdgcn_exp2f(x);      // bare v_exp_f32
#else
    return __expf(x * 0.69314718056f);
#endif
}

// VALU-pipe partial-sum step: v += lane(l-n) within each 16-lane DPP row,
// 0-filled at the edge. After 1,2,4,8 lane 15 holds the 16-lane sum.
// (HW-verified in R4/R5 runs.)
template <int CTRL>
__device__ __forceinline__ float dpp_sr_add(float v) {
    int s = __builtin_amdgcn_update_dpp(0, __float_as_int(v), CTRL, 0xf, 0xf, true);
    return v + __int_as_float(s);
}
__device__ __forceinline__ float row16_sum(float v) {
    v = dpp_sr_add<0x111>(v);   // row_shr:1
    v = dpp_sr_add<0x112>(v);   // row_shr:2
    v = dpp_sr_add<0x114>(v);   // row_shr:4
    v = dpp_sr_add<0x118>(v);   // row_shr:8
    return v;                   // valid in lane 15 of each 16-lane row
}

// ---------------------------------------------------------------- kernel 1
// Both inputs -> fragment-major bf16. Frag semantics (R0-verified):
//   lane l of tile (r16,kk) holds M[r16*16 + (l&15)][kk*32 + (l>>4)*8 .. +8]
__global__ void convert_pack(const float* __restrict__ a,
                             const float* __restrict__ t,
                             ushort* __restrict__ oa,
                             ushort* __restrict__ ot) {
    int idx = blockIdx.x * 256 + threadIdx.x;          // 0 .. 262143
    const float* src = (idx >> 17) ? t : a;
    ushort*      dst = (idx >> 17) ? ot : oa;
    int loc = idx & 131071;
    int l = loc & 63, tile = loc >> 6;
    int kk = tile & 3, r16 = tile >> 2;
    int row = r16 * 16 + (l & 15);
    int k0  = kk * 32 + (l >> 4) * 8;
    const float4* s4 = reinterpret_cast<const float4*>(src + row * 128 + k0);
    float4 f0 = s4[0], f1 = s4[1];
    uint4 o;
    o.x = f2bf(f0.x) | ((unsigned)f2bf(f0.y) << 16);
    o.y = f2bf(f0.z) | ((unsigned)f2bf(f0.w) << 16);
    o.z = f2bf(f1.x) | ((unsigned)f2bf(f1.y) << 16);
    o.w = f2bf(f1.z) | ((unsigned)f2bf(f1.w) << 16);
    *reinterpret_cast<uint4*>(dst + loc * 8) = o;
}

// ---------------------------------------------------------------- kernel 2
// Independent 64x128 wave-tiles. af[4][4] pinned; B in 4 phases of 32 cols
// (bf[2][4] + acc[4][2] reused each phase -> peak live ~160 regs). No LDS,
// no barriers. XCD-bijective swizzle: 8 col-strips (1024 cols, 256 KB of T)
// per XCD + all of A (2 MB) = 2.25 MB < 4 MB L2.
__global__ void __launch_bounds__(256)
gemm_exp(const ushort* __restrict__ Ap, const ushort* __restrict__ Tp,
         const float* __restrict__ temps,
         float* __restrict__ Pi, float* __restrict__ Pj) {
    const int tid = threadIdx.x;
    const int wave = tid >> 6, lane = tid & 63;
    const int krow = lane >> 4, lcol = lane & 15;
    const int fid = blockIdx.x;                        // 0..2047
    const int vid = (fid & 7) * 256 + (fid >> 3);      // bijective (2048%8==0)
    const int j  = vid >> 5;                           // col-strip (128 cols) 0..63
    const int rg = vid & 31;                           // row-group (256 rows) 0..31
    const int rs = rg * 4 + wave;                      // row-strip (64 rows) 0..127

    const float sc2 = __expf(temps[0]) * 1.44269504f;  // exp(temp)*log2(e)

    // A fragments: 16 coalesced 1 KiB wave-loads, held for all 4 phases
    bf16x8 af[4][4];
#pragma unroll
    for (int m = 0; m < 4; ++m)
#pragma unroll
        for (int kk = 0; kk < 4; ++kk)
            af[m][kk] = *reinterpret_cast<const bf16x8*>(
                Ap + (((rs * 4 + m) * 4 + kk) * 64 + lane) * 8);

    float rsum[4][4] = {};

#pragma unroll
    for (int ph = 0; ph < 4; ++ph) {
        bf16x8 bf[2][4];
#pragma unroll
        for (int n = 0; n < 2; ++n)
#pragma unroll
            for (int kk = 0; kk < 4; ++kk)
                bf[n][kk] = *reinterpret_cast<const bf16x8*>(
                    Tp + (((j * 8 + ph * 2 + n) * 4 + kk) * 64 + lane) * 8);

        f32x4 acc[4][2];
#pragma unroll
        for (int m = 0; m < 4; ++m)
#pragma unroll
            for (int n = 0; n < 2; ++n)
                acc[m][n] = (f32x4){0.f, 0.f, 0.f, 0.f};

#pragma unroll
        for (int kk = 0; kk < 4; ++kk)
#pragma unroll
            for (int m = 0; m < 4; ++m)
#pragma unroll
                for (int n = 0; n < 2; ++n)
                    acc[m][n] = __builtin_amdgcn_mfma_f32_16x16x32_bf16(
                        af[m][kk], bf[n][kk], acc[m][n], 0, 0, 0);

        // epilogue for these 32 cols: exp2, row-acc (regs), col partials out
        float csum[2] = {0.f, 0.f};
#pragma unroll
        for (int m = 0; m < 4; ++m)
#pragma unroll
            for (int n = 0; n < 2; ++n)
#pragma unroll
                for (int jj = 0; jj < 4; ++jj) {
                    float v = fast_exp2(acc[m][n][jj] * sc2);
                    rsum[m][jj] += v;
                    csum[n] += v;
                }
#pragma unroll
        for (int n = 0; n < 2; ++n) {
            float v = csum[n];
            v += __shfl_xor(v, 16); v += __shfl_xor(v, 32);
            if (lane < 16) {
                int col = (j * 8 + ph * 2 + n) * 16 + lcol;
                Pj[col * 128 + rs] = v;
            }
        }
    }

    // row sums over this wave's 128 cols: DPP reduce, lane 15 of each krow row
#pragma unroll
    for (int m = 0; m < 4; ++m)
#pragma unroll
        for (int jj = 0; jj < 4; ++jj) {
            float v = row16_sum(rsum[m][jj]);
            if (lcol == 15) {
                int row = rs * 64 + m * 16 + krow * 4 + jj;
                Pi[row * 64 + j] = v;
            }
        }
}

// ---------------------------------------------------------------- kernel 3
// One wave per row, 4 rows/block; partials transposed so reads coalesce.
__global__ void finalize_rows(const float* __restrict__ a, const float* __restrict__ t,
                              const float* __restrict__ temps,
                              const float* __restrict__ Pi, const float* __restrict__ Pj,
                              float* __restrict__ loss) {
    const int r = blockIdx.x * 4 + (threadIdx.x >> 6);
    const int l = threadIdx.x & 63;
    const float sc = __expf(temps[0]);
    float deni = Pi[r * 64 + l];
    float denj = Pj[r * 128 + l] + Pj[r * 128 + 64 + l];
    float dotp = a[r * 128 + l] * t[r * 128 + l]
               + a[r * 128 + 64 + l] * t[r * 128 + 64 + l];
#pragma unroll
    for (int m = 1; m < 64; m <<= 1) {
        deni += __shfl_xor(deni, m);
        denj += __shfl_xor(denj, m);
        dotp += __shfl_xor(dotp, m);
    }
    if (l == 0) {
        float diag = __expf(sc * dotp);
        float di = fmaxf(deni - diag, 1e-20f);
        float dj = fmaxf(denj - diag, 1e-20f);
        loss[r] = -sc * dotp + 0.5f * (__logf(di) + __logf(dj));
    }
}

// ---------------------------------------------------------------- kernel 4
__global__ void reduce_loss(const float* __restrict__ loss, float* __restrict__ out) {
    __shared__ float wsum[16];
    const int tid = threadIdx.x;   // 1024
    float s = 0.f;
#pragma unroll
    for (int i = 0; i < 8; ++i) s += loss[tid + i * 1024];
#pragma unroll
    for (int m = 1; m < 64; m <<= 1) s += __shfl_xor(s, m);
    if ((tid & 63) == 0) wsum[tid >> 6] = s;
    __syncthreads();
    if (tid == 0) {
        float acc = 0.f;
#pragma unroll
        for (int w = 0; w < 16; ++w) acc += wsum[w];
        out[0] = acc * (1.0f / 8192.0f);
    }
}

extern "C" void kernel_launch(void* const* d_in, const int* in_sizes, int n_in,
                              void* d_out, int out_size, void* d_ws, size_t ws_size,
                              hipStream_t stream) {
    const float* a     = (const float*)d_in[0];
    const float* t     = (const float*)d_in[1];
    const float* temps = (const float*)d_in[2];
    float* out = (float*)d_out;

    char* ws = (char*)d_ws;
    ushort* Ap  = (ushort*)(ws);
    ushort* Tp  = (ushort*)(ws + (2u << 20));
    float*  Pi  = (float*)(ws + (4u << 20));
    float*  Pj  = (float*)(ws + (6u << 20));
    float*  los = (float*)(ws + (10u << 20));

    convert_pack<<<1024, 256, 0, stream>>>(a, t, Ap, Tp);
    gemm_exp<<<2048, 256, 0, stream>>>(Ap, Tp, temps, Pi, Pj);
    finalize_rows<<<2048, 256, 0, stream>>>(a, t, temps, Pi, Pj, los);
    reduce_loss<<<1, 1024, 0, stream>>>(los, out);
}